// Round 2
// baseline (1139.387 us; speedup 1.0000x reference)
//
#include <hip/hip_runtime.h>
#include <math.h>

// AttentionEncoder: per node, attention over its K=32 neighbors (D=128).
// One wave (64 lanes) per node; lane owns 2 dims (float2). Neighbor slab
// (32 x float2 per lane = 64 VGPRs) is read from HBM exactly once and
// reused from registers for both the score dot-products and the weighted
// aggregation.
//
// R1 change vs previous best (1028.5 us): replace the full 64-lane xor
// butterfly (192 ds-ops, then 32 expf per lane) with a tree-exchange
// reduction (32 ds-ops) that leaves ONE complete score per lane
// (k = bitrev5(lane&31)), a distributed softmax (10 ds-ops, 1 expf/lane),
// and a v_readlane weight broadcast (0 ds-ops, weights land in SGPRs).
// Cross-lane ops per wave: 192 -> 42. Theory: kernel was cross-lane/VALU
// bound at ~13% of HBM roofline.
//
// R2: resubmitted unchanged — R0/R1 benches both died with "container
// failed twice" (infra, not kernel: R0's source was previously
// harness-verified). Need a clean measurement of this single change.

constexpr int D = 128;
constexpr int K = 32;
constexpr int WAVES_PER_BLOCK = 4;

// After the tree exchange, score k lives on lane bitrev5(k) (and its +32 twin).
__host__ __device__ constexpr int lane_of_k(int k) {
    return ((k & 1) << 4) | ((k & 2) << 2) | (k & 4) | ((k & 8) >> 2) | ((k & 16) >> 4);
}

__global__ __launch_bounds__(256)
void AttentionEncoder_32650341384783_kernel(const float* __restrict__ h_n,
                                            const float* __restrict__ neighbor,
                                            float* __restrict__ out, int N) {
    const int wave = threadIdx.x >> 6;
    const int lane = threadIdx.x & 63;
    const int n = blockIdx.x * WAVES_PER_BLOCK + wave;
    if (n >= N) return;

    const int d0 = lane * 2;  // this lane's 2 dims
    const float2 h = *(const float2*)(h_n + (size_t)n * D + d0);
    const float* nb_base = neighbor + (size_t)n * K * D + d0;

    // Load all 32 neighbor fragments (512B coalesced per instruction,
    // 32 independent loads in flight per wave). Read from HBM exactly once.
    float2 nb[K];
#pragma unroll
    for (int k = 0; k < K; ++k) {
        nb[k] = *(const float2*)(nb_base + (size_t)k * D);
    }

    // Per-lane partial dot products.
    float p[K];
#pragma unroll
    for (int k = 0; k < K; ++k) {
        p[k] = h.x * nb[k].x + h.y * nb[k].y;
    }

    // Tree exchange: at each level send the partner the half it keeps.
    // 16+8+4+2+1 shuffles reduce 32 partials across each 32-lane half;
    // value-index i at the end maps to k with bit j of lane -> bit (4-j) of k.
    // In-place safe: p[i] written after p[i+half] read (i < i+half).
#pragma unroll
    for (int j = 0; j < 5; ++j) {
        const int o = 1 << j;
        const int half = 16 >> j;
        const bool hi = (lane >> j) & 1;
#pragma unroll
        for (int i = 0; i < half; ++i) {
            const float keep = hi ? p[i + half] : p[i];
            const float give = hi ? p[i] : p[i + half];
            p[i] = keep + __shfl_xor(give, o, 64);
        }
    }
    // Cross the 32-lane halves: full 64-lane dot product for k = bitrev5(lane&31).
    float s = p[0] + __shfl_xor(p[0], 32, 64);
    s *= 0.08838834764831845f;  // 1/sqrt(128)

    // Distributed softmax: each 32-lane half holds all 32 distinct scores
    // exactly once, so a 5-step butterfly within the half gives true max/sum.
    float m = s;
#pragma unroll
    for (int o = 1; o < 32; o <<= 1) {
        m = fmaxf(m, __shfl_xor(m, o, 64));
    }
    const float e = __expf(s - m);
    float sum = e;
#pragma unroll
    for (int o = 1; o < 32; o <<= 1) {
        sum += __shfl_xor(sum, o, 64);
    }
    const float w = e * (1.0f / sum);  // this lane's weight for its k

    // Weight broadcast via v_readlane (VALU, no DS pipe): weight k lives on
    // lane bitrev5(k); readlane with a compile-time lane index lands it in an
    // SGPR, legal as the one scalar operand of v_fma.
    float aggx = 0.0f, aggy = 0.0f;
#pragma unroll
    for (int k = 0; k < K; ++k) {
        const float wk = __uint_as_float((unsigned)__builtin_amdgcn_readlane(
            (int)__float_as_uint(w), lane_of_k(k)));
        aggx = fmaf(wk, nb[k].x, aggx);
        aggy = fmaf(wk, nb[k].y, aggy);
    }

    float2 o2;
    o2.x = h.x + aggx;
    o2.y = h.y + aggy;
    *(float2*)(out + (size_t)n * D + d0) = o2;
}

extern "C" void kernel_launch(void* const* d_in, const int* in_sizes, int n_in,
                              void* d_out, int out_size, void* d_ws, size_t ws_size,
                              hipStream_t stream) {
    const float* h_n = (const float*)d_in[0];
    const float* neighbor = (const float*)d_in[1];
    float* out = (float*)d_out;
    const int N = in_sizes[0] / D;  // B*N nodes (B=1)

    const int blocks = (N + WAVES_PER_BLOCK - 1) / WAVES_PER_BLOCK;
    AttentionEncoder_32650341384783_kernel<<<blocks, WAVES_PER_BLOCK * 64, 0, stream>>>(
        h_n, neighbor, out, N);
}